// Round 7
// baseline (14972.498 us; speedup 1.0000x reference)
//
#include <hip/hip_runtime.h>
#include <hip/hip_bf16.h>
#include <hip/hip_fp16.h>

#define NF    15
#define NBF   20
#define TT    1760
#define TS    880
#define EP    64
#define ES    128
#define DF    128
#define H1    384
#define G3    1152
#define INA   896
#define JREP  11

typedef _Float16 h2v __attribute__((ext_vector_type(2)));

__device__ __forceinline__ float sigmf_(float x){ return 1.0f/(1.0f + __expf(-x)); }
__device__ __forceinline__ float tanhf_(float x){ return 2.0f/(1.0f + __expf(-2.0f*x)) - 1.0f; }
__device__ __forceinline__ h2v bc_h2(unsigned u){ return __builtin_bit_cast(h2v, u); }
__device__ __forceinline__ float fdot2_(h2v a, h2v b, float c){
#if __has_builtin(__builtin_amdgcn_fdot2)
  return __builtin_amdgcn_fdot2(a, b, c, false);
#else
  return c + (float)a[0]*(float)b[0] + (float)a[1]*(float)b[1];
#endif
}

// ---------------- frame-rate network: f[64][11][128] ----------------
__global__ __launch_bounds__(128) void k_frame(const float* feat, const int* periods, const float* embp,
   const float* c1w, const float* c1b, const float* c2w, const float* c2b,
   const float* f1w, const float* f1b, const float* f2w, const float* f2b, float* fout)
{
  __shared__ float cat[NF*84];
  __shared__ float x1[13*DF];
  __shared__ float x2[JREP*DF];
  int b = blockIdx.x, tid = threadIdx.x;
  for (int idx = tid; idx < NF*84; idx += 128){
    int j = idx/84, c = idx%84;
    cat[idx] = (c < NBF) ? feat[(b*NF+j)*NBF + c]
                         : embp[periods[b*NF+j]*EP + (c-NBF)];
  }
  __syncthreads();
  int o = tid;
  for (int p = 0; p < 13; ++p){
    float acc = c1b[o];
    for (int kk = 0; kk < 3; ++kk)
      for (int c = 0; c < 84; ++c)
        acc += cat[(p+kk)*84 + c] * c1w[(o*84+c)*3+kk];
    x1[p*DF+o] = tanhf_(acc);
  }
  __syncthreads();
  for (int p = 0; p < JREP; ++p){
    float acc = c2b[o];
    for (int kk = 0; kk < 3; ++kk)
      for (int c = 0; c < DF; ++c)
        acc += x1[(p+kk)*DF+c] * c2w[(o*DF+c)*3+kk];
    x2[p*DF+o] = tanhf_(acc);
  }
  __syncthreads();
  for (int p = 0; p < JREP; ++p){
    float acc = f1b[o];
    for (int c = 0; c < DF; ++c) acc += x2[p*DF+c]*f1w[o*DF+c];
    x1[p*DF+o] = tanhf_(acc);
  }
  __syncthreads();
  for (int p = 0; p < JREP; ++p){
    float acc = f2b[o];
    for (int c = 0; c < DF; ++c) acc += x1[p*DF+c]*f2w[o*DF+c];
    fout[(b*JREP+p)*DF+o] = tanhf_(acc);
  }
}

// ---------------- pack ga_whh f32 -> per-thread-contiguous f16 (768-thread single-block scan) ----
// element o = (n*768 + tid)*8 + c*2 + u  (uint4 n in [0,72), dword c, half u)
// thread tid: i = tid%384, jh = tid/384. gd = n*4+c in [0,288): q=gd/6, k6=gd%6,
// g=k6>>1, hsel=k6&1 ; j = jh*192 + 4q + 2*hsel + u ; w = whh[(g*H1+i)*H1 + j]
__global__ __launch_bounds__(256) void k_wpack4(const float* whh, _Float16* wpk){
  int o = blockIdx.x*256 + threadIdx.x;        // < 442368
  int u  = o & 1;
  int c  = (o >> 1) & 3;
  int q4 = o >> 3;
  int tid = q4 % 768;
  int n   = q4 / 768;
  int i = tid % 384, jh = tid / 384;
  int gd = n*4 + c;
  int q = gd / 6, k6 = gd % 6;
  int g = k6 >> 1, hsel = k6 & 1;
  int j = jh*192 + 4*q + 2*hsel + u;
  wpk[o] = (_Float16)whh[(g*H1 + i)*H1 + j];
}

// ---------------- GA tables: GA[k][256][1152] ----------------
__global__ __launch_bounds__(256) void k_tables(const float* wih, const float* emb, float* GA){
  __shared__ float Wl[64*129];
  int k = blockIdx.x/18, g0 = (blockIdx.x%18)*64;
  int tid = threadIdx.x;
  for (int idx = tid; idx < 64*128; idx += 256){
    int gg = idx>>7, c = idx&127;
    Wl[gg*129+c] = wih[(size_t)(g0+gg)*INA + k*128 + c];
  }
  __syncthreads();
  int vv = tid>>6, gg = tid&63;
  for (int v = vv; v < 256; v += 4){
    const float* e = emb + (size_t)v*ES;
    float acc = 0.f;
    for (int c = 0; c < 128; ++c) acc += e[c]*Wl[gg*129+c];
    GA[(size_t)(k*256+v)*G3 + g0+gg] = acc;
  }
}

// ---------------- xWrepA[b][j][1152] ----------------
__global__ __launch_bounds__(256) void k_xwrepA(const float* wih, const float* f,
                                                const float* bih, const float* bhh, float* xwA){
  __shared__ float Wl[64*129];
  int g0 = blockIdx.x*64, tid = threadIdx.x;
  for (int idx = tid; idx < 64*128; idx += 256){
    int gg = idx>>7, c = idx&127;
    Wl[gg*129+c] = wih[(size_t)(g0+gg)*INA + 768 + c];
  }
  __syncthreads();
  int vv = tid>>6, gg = tid&63; int g = g0+gg;
  float badd = bih[g] + (g < 768 ? bhh[g] : 0.f);
  for (int row = vv; row < 64*JREP; row += 4){
    const float* fr = f + (size_t)row*DF;
    float acc = badd;
    for (int c = 0; c < 128; ++c) acc += fr[c]*Wl[gg*129+c];
    xwA[(size_t)row*G3 + g] = acc;
  }
}

// ---------------- xWrepB[b][j][48] ----------------
__global__ __launch_bounds__(256) void k_xwrepB(const float* wih, const float* f,
                                                const float* bih, const float* bhh, float* xwB){
  __shared__ float Wl[48*129];
  int b = blockIdx.x, tid = threadIdx.x;
  for (int idx = tid; idx < 48*128; idx += 256){
    int r = idx>>7, c = idx&127;
    Wl[r*129+c] = wih[r*512 + 384 + c];
  }
  __syncthreads();
  for (int idx = tid; idx < JREP*48; idx += 256){
    int j = idx/48, r = idx%48;
    const float* fr = f + (size_t)(b*JREP+j)*DF;
    float acc = bih[r] + (r < 32 ? bhh[r] : 0.f);
    for (int c = 0; c < 128; ++c) acc += fr[c]*Wl[r*129+c];
    xwB[(size_t)(b*JREP+j)*48 + r] = acc;
  }
}

// ---------------- md2 embed tables: T2[tbl][256][256] ----------------
__global__ __launch_bounds__(256) void k_t2(const float* w1, const float* w2, const float* emb, float* T2){
  __shared__ float Wl[64*129];
  int tbl = blockIdx.x>>2; int c0 = (blockIdx.x&3)*64; int tid = threadIdx.x;
  const float* w = tbl ? w2 : w1;
  for (int idx = tid; idx < 64*128; idx += 256){
    int cc = idx>>7, e = idx&127;
    Wl[cc*129+e] = w[(c0+cc)*144 + 16 + e];
  }
  __syncthreads();
  int vv = tid>>6, cc = tid&63;
  for (int v = vv; v < 256; v += 4){
    const float* e = emb + (size_t)v*ES;
    float acc = 0.f;
    for (int c = 0; c < 128; ++c) acc += e[c]*Wl[cc*129+c];
    T2[tbl*65536 + v*256 + c0+cc] = acc;
  }
}

// ---------------- GRU-A scan v6: ONE block per batch, all weights CU-resident ----------------
#define LDW(n) uint4 d##n = wsrc[(size_t)(n)*768];
#define Q2(A,B,C, q2) { \
  h2v hA = hh[jb2 + (q2)*2],     hB = hh[jb2 + (q2)*2 + 1]; \
  ar = fdot2_(hA, bc_h2(A.x), ar); ar = fdot2_(hB, bc_h2(A.y), ar); \
  az = fdot2_(hA, bc_h2(A.z), az); az = fdot2_(hB, bc_h2(A.w), az); \
  an = fdot2_(hA, bc_h2(B.x), an); an = fdot2_(hB, bc_h2(B.y), an); \
  h2v hC = hh[jb2 + (q2)*2 + 2], hD = hh[jb2 + (q2)*2 + 3]; \
  ar = fdot2_(hC, bc_h2(B.z), ar); ar = fdot2_(hD, bc_h2(B.w), ar); \
  az = fdot2_(hC, bc_h2(C.x), az); az = fdot2_(hD, bc_h2(C.y), az); \
  an = fdot2_(hC, bc_h2(C.z), an); an = fdot2_(hD, bc_h2(C.w), an); }
#define DOTS24 \
  Q2(d0,d1,d2,0)    Q2(d3,d4,d5,2)    Q2(d6,d7,d8,4)    Q2(d9,d10,d11,6) \
  Q2(d12,d13,d14,8) Q2(d15,d16,d17,10) Q2(d18,d19,d20,12) Q2(d21,d22,d23,14) \
  Q2(d24,d25,d26,16) Q2(d27,d28,d29,18) Q2(d30,d31,d32,20) Q2(d33,d34,d35,22) \
  Q2(d36,d37,d38,24) Q2(d39,d40,d41,26) Q2(d42,d43,d44,28) Q2(d45,d46,d47,30) \
  Q2(d48,d49,d50,32) Q2(d51,d52,d53,34) Q2(d54,d55,d56,36) Q2(d57,d58,d59,38) \
  Q2(d60,d61,d62,40) Q2(d63,d64,d65,42) Q2(d66,d67,d68,44) Q2(d69,d70,d71,46)

__global__ __launch_bounds__(768, 3) void k_scanA6(const int* __restrict__ in_data,
        const float* __restrict__ GA, const float* __restrict__ xwA,
        const uint4* __restrict__ wpk, const float* __restrict__ bhh,
        unsigned* __restrict__ g1u)
{
  __shared__ __align__(16) unsigned h16u[192];   // full h as 192 u32 (f16 pairs)
  __shared__ __align__(8)  float pg[3][2][384];  // dot partials [gate][jh][row]
  __shared__ __align__(8)  float xwb[2][G3];     // xW double buffer [buf][col]
  __shared__ int indr[2][8];
  const int b = blockIdx.x;
  const int tid = threadIdx.x;
  const int i  = tid % 384;                      // output row
  const int jh = tid / 384;                      // j half (0/1)
  const int jb2 = jh * 96;                       // h2 base (u32 index)
  const int* ind_b = in_data + (size_t)b*TT*3;

  // weights: 72 uint4 (288 u32) per thread, loaded once into unified VGPR/AGPR file
  const uint4* wsrc = wpk + tid;
  LDW(0)  LDW(1)  LDW(2)  LDW(3)  LDW(4)  LDW(5)  LDW(6)  LDW(7)  LDW(8)
  LDW(9)  LDW(10) LDW(11) LDW(12) LDW(13) LDW(14) LDW(15) LDW(16) LDW(17)
  LDW(18) LDW(19) LDW(20) LDW(21) LDW(22) LDW(23) LDW(24) LDW(25) LDW(26)
  LDW(27) LDW(28) LDW(29) LDW(30) LDW(31) LDW(32) LDW(33) LDW(34) LDW(35)
  LDW(36) LDW(37) LDW(38) LDW(39) LDW(40) LDW(41) LDW(42) LDW(43) LDW(44)
  LDW(45) LDW(46) LDW(47) LDW(48) LDW(49) LDW(50) LDW(51) LDW(52) LDW(53)
  LDW(54) LDW(55) LDW(56) LDW(57) LDW(58) LDW(59) LDW(60) LDW(61) LDW(62)
  LDW(63) LDW(64) LDW(65) LDW(66) LDW(67) LDW(68) LDW(69) LDW(70) LDW(71)

  const bool isG = (tid < 576);                  // gather role: 2 cols each
  const int  c0 = 2*tid, c1 = 2*tid + 1;

  float hreg0 = 0.f, hreg1 = 0.f, bn0 = 0.f, bn1 = 0.f;
  if (tid < 192){
    bn0 = bhh[768 + 2*tid];
    bn1 = bhh[768 + 2*tid + 1];
    h16u[tid] = 0u;
  }
  // prologue: xwb[0] for t=0 ; indices for t=1
  if (isG){
    float s0 = xwA[(size_t)(b*JREP)*G3 + c0];
    float s1 = xwA[(size_t)(b*JREP)*G3 + c1];
    #pragma unroll
    for (int k2 = 0; k2 < 6; ++k2){
      int v = ind_b[k2];
      s0 += GA[((size_t)k2*256 + v)*G3 + c0];
      s1 += GA[((size_t)k2*256 + v)*G3 + c1];
    }
    xwb[0][c0] = s0; xwb[0][c1] = s1;
  }
  if (tid >= 576 && tid < 582) indr[1][tid-576] = ind_b[6 + (tid-576)];
  const h2v* hh = (const h2v*)h16u;
  __syncthreads();

  for (int t = 0; t < TS; ++t){
    const int nb = t & 1;
    // ---- issue gathers for t+1 (summed after dots) ----
    const int tp = t + 1;
    float ga0=0.f,ga1=0.f,ga2=0.f,ga3=0.f,ga4=0.f,ga5=0.f,gx0=0.f;
    float gb0=0.f,gb1=0.f,gb2=0.f,gb3=0.f,gb4=0.f,gb5=0.f,gx1=0.f;
    if (tp < TS && isG){
      int v0=indr[tp&1][0], v1=indr[tp&1][1], v2=indr[tp&1][2];
      int v3=indr[tp&1][3], v4=indr[tp&1][4], v5=indr[tp&1][5];
      const float* xwr = xwA + ((size_t)(b*JREP) + tp/80)*G3;
      ga0 = GA[((size_t)0*256 + v0)*G3 + c0]; gb0 = GA[((size_t)0*256 + v0)*G3 + c1];
      ga1 = GA[((size_t)1*256 + v1)*G3 + c0]; gb1 = GA[((size_t)1*256 + v1)*G3 + c1];
      ga2 = GA[((size_t)2*256 + v2)*G3 + c0]; gb2 = GA[((size_t)2*256 + v2)*G3 + c1];
      ga3 = GA[((size_t)3*256 + v3)*G3 + c0]; gb3 = GA[((size_t)3*256 + v3)*G3 + c1];
      ga4 = GA[((size_t)4*256 + v4)*G3 + c0]; gb4 = GA[((size_t)4*256 + v4)*G3 + c1];
      ga5 = GA[((size_t)5*256 + v5)*G3 + c0]; gb5 = GA[((size_t)5*256 + v5)*G3 + c1];
      gx0 = xwr[c0]; gx1 = xwr[c1];
    }
    int iv = 0;
    const int stg = t + 2;
    const bool doStg = (tid >= 576 && tid < 582 && stg < TS);
    if (doStg) iv = ind_b[6*stg + (tid-576)];
    // ---- dots: 288 fdot2 against resident weights, h broadcast from LDS ----
    float ar=0.f, az=0.f, an=0.f;
    DOTS24
    pg[0][jh][i] = ar; pg[1][jh][i] = az; pg[2][jh][i] = an;
    // ---- finalize gathers ----
    if (tp < TS && isG){
      xwb[tp&1][c0] = ga0+ga1+ga2+ga3+ga4+ga5+gx0;
      xwb[tp&1][c1] = gb0+gb1+gb2+gb3+gb4+gb5+gx1;
    }
    if (doStg) indr[t&1][tid-576] = iv;
    __syncthreads();
    // ---- epilogue: 192 threads, 2 rows each ----
    if (tid < 192){
      float2 pr0 = *(const float2*)&pg[0][0][2*tid];
      float2 pr1 = *(const float2*)&pg[0][1][2*tid];
      float2 pz0 = *(const float2*)&pg[1][0][2*tid];
      float2 pz1 = *(const float2*)&pg[1][1][2*tid];
      float2 pn0 = *(const float2*)&pg[2][0][2*tid];
      float2 pn1 = *(const float2*)&pg[2][1][2*tid];
      float2 xr = *(const float2*)&xwb[nb][2*tid];
      float2 xz = *(const float2*)&xwb[nb][384 + 2*tid];
      float2 xn = *(const float2*)&xwb[nb][768 + 2*tid];
      float rr0 = sigmf_(pr0.x + pr1.x + xr.x);
      float zz0 = sigmf_(pz0.x + pz1.x + xz.x);
      float nn0 = tanhf_(xn.x + rr0*(pn0.x + pn1.x + bn0));
      float h0 = (1.f - zz0)*nn0 + zz0*hreg0; hreg0 = h0;
      float rr1 = sigmf_(pr0.y + pr1.y + xr.y);
      float zz1 = sigmf_(pz0.y + pz1.y + xz.y);
      float nn1 = tanhf_(xn.y + rr1*(pn0.y + pn1.y + bn1));
      float h1 = (1.f - zz1)*nn1 + zz1*hreg1; hreg1 = h1;
      unsigned pack = (unsigned)__builtin_bit_cast(unsigned short, (_Float16)h0)
                    | ((unsigned)__builtin_bit_cast(unsigned short, (_Float16)h1) << 16);
      h16u[tid] = pack;
      g1u[((size_t)b*TS + t)*192 + tid] = pack;
    }
    __syncthreads();
  }
}

// ---------------- xW_B = g1 @ gb_wih[:, :384].T + xWrepB ----------------
__global__ __launch_bounds__(256) void k_xwB(const _Float16* g1, const float* wih,
                                             const float* xwrB, float* xwB){
  __shared__ _Float16 gl[16*392];
  int bi = blockIdx.x; int b = bi/55; int t0 = (bi%55)*16; int tid = threadIdx.x;
  for (int idx = tid; idx < 16*H1; idx += 256){
    int tt = idx/H1, c = idx%H1;
    gl[tt*392+c] = g1[((size_t)b*TS + t0+tt)*H1 + c];
  }
  __syncthreads();
  int rr = tid>>4, tt = tid&15;
  int t = t0+tt;
  const float* xr = xwrB + ((size_t)(b*JREP) + t/80)*48;
  for (int rb = 0; rb < 3; ++rb){
    int r = rb*16 + rr;
    const float* wrow = wih + (size_t)r*512;
    float acc = 0.f;
    for (int c = 0; c < H1; ++c) acc += (float)gl[tt*392+c]*wrow[c];
    xwB[((size_t)b*TS + t)*48 + r] = acc + xr[r];
  }
}

// ---------------- GRU-B scan (tiny) ----------------
__global__ __launch_bounds__(64) void k_scanB(const float* xwB, const float* whh,
                                              const float* bhh, float* g2){
  __shared__ float wl[48*17];
  __shared__ float h2s[16];
  __shared__ float pre[32];
  __shared__ float xn[16], gn[16];
  int b = blockIdx.x, tid = threadIdx.x;
  for (int idx = tid; idx < 768; idx += 64) wl[(idx>>4)*17 + (idx&15)] = whh[idx];
  if (tid < 16) h2s[tid] = 0.f;
  float bn = (tid >= 32 && tid < 48) ? bhh[tid] : 0.f;
  __syncthreads();
  for (int t = 0; t < TS; ++t){
    if (tid < 48){
      float xw = xwB[((size_t)b*TS + t)*48 + tid];
      float gh = 0.f;
      for (int e = 0; e < 16; ++e) gh += wl[tid*17+e]*h2s[e];
      if (tid < 32) pre[tid] = xw + gh;
      else { xn[tid-32] = xw; gn[tid-32] = gh + bn; }
    }
    __syncthreads();
    if (tid < 16){
      float r = sigmf_(pre[tid]), z = sigmf_(pre[16+tid]);
      float n = tanhf_(xn[tid] + r*gn[tid]);
      float hn = (1.f - z)*n + z*h2s[tid];
      h2s[tid] = hn;
      g2[((size_t)b*TS + t)*16 + tid] = hn;
    }
    __syncthreads();
  }
}

// ---------------- mdense + output interleave ----------------
__global__ __launch_bounds__(256) void k_out(const float* g2, const int* targets, const float* T2,
    const float* m1w1, const float* m1w2, const float* m1b1, const float* m1b2,
    const float* m1f1, const float* m1f2,
    const float* m2w1, const float* m2w2, const float* m2b1, const float* m2b2,
    const float* m2f1, const float* m2f2, float* out)
{
  __shared__ float wA[256*17], wB[256*17], wC[256*17], wD[256*17];
  __shared__ float g2l[16*16];
  int bi = blockIdx.x; int b = bi/55; int t0 = (bi%55)*16; int c = threadIdx.x;
  for (int d = 0; d < 16; ++d){
    wA[c*17+d] = m1w1[c*16+d];  wB[c*17+d] = m1w2[c*16+d];
    wC[c*17+d] = m2w1[c*144+d]; wD[c*17+d] = m2w2[c*144+d];
  }
  { int tt = c>>4, d = c&15; g2l[c] = g2[((size_t)b*TS + t0+tt)*16 + d]; }
  __syncthreads();
  float b1a = m1b1[c], b2a = m1b2[c], f1a = m1f1[c], f2a = m1f2[c];
  float b1b = m2b1[c], b2b = m2b2[c], f1b = m2f1[c], f2b = m2f2[c];
  for (int tt = 0; tt < 16; ++tt){
    int t = t0+tt;
    float d1 = b1a, d2 = b2a, e1 = b1b, e2 = b2b;
    for (int d = 0; d < 16; ++d){
      float g = g2l[tt*16+d];
      d1 += g*wA[c*17+d]; d2 += g*wB[c*17+d];
      e1 += g*wC[c*17+d]; e2 += g*wD[c*17+d];
    }
    int v = targets[b*TT + 2*t];
    e1 += T2[v*256+c]; e2 += T2[65536 + v*256+c];
    float o1 = f1a*tanhf_(d1) + f2a*tanhf_(d2);
    float o2 = f1b*tanhf_(e1) + f2b*tanhf_(e2);
    size_t base = ((size_t)b*TS + t)*2*256;
    out[base + c]       = o1;
    out[base + 256 + c] = o2;
  }
}

extern "C" void kernel_launch(void* const* d_in, const int* in_sizes, int n_in,
                              void* d_out, int out_size, void* d_ws, size_t ws_size,
                              hipStream_t stream) {
  const int*   in_data = (const int*)  d_in[0];
  const float* feat    = (const float*)d_in[1];
  const int*   periods = (const int*)  d_in[2];
  const int*   targets = (const int*)  d_in[3];
  const float* embp    = (const float*)d_in[4];
  const float* embs    = (const float*)d_in[5];
  const float* c1w = (const float*)d_in[6];  const float* c1b = (const float*)d_in[7];
  const float* c2w = (const float*)d_in[8];  const float* c2b = (const float*)d_in[9];
  const float* f1w = (const float*)d_in[10]; const float* f1b = (const float*)d_in[11];
  const float* f2w = (const float*)d_in[12]; const float* f2b = (const float*)d_in[13];
  const float* ga_wih = (const float*)d_in[14]; const float* ga_whh = (const float*)d_in[15];
  const float* ga_bih = (const float*)d_in[16]; const float* ga_bhh = (const float*)d_in[17];
  const float* gb_wih = (const float*)d_in[18]; const float* gb_whh = (const float*)d_in[19];
  const float* gb_bih = (const float*)d_in[20]; const float* gb_bhh = (const float*)d_in[21];
  const float* m1w1 = (const float*)d_in[22]; const float* m1w2 = (const float*)d_in[23];
  const float* m1b1 = (const float*)d_in[24]; const float* m1b2 = (const float*)d_in[25];
  const float* m1f1 = (const float*)d_in[26]; const float* m1f2 = (const float*)d_in[27];
  const float* m2w1 = (const float*)d_in[28]; const float* m2w2 = (const float*)d_in[29];
  const float* m2b1 = (const float*)d_in[30]; const float* m2b2 = (const float*)d_in[31];
  const float* m2f1 = (const float*)d_in[32]; const float* m2f2 = (const float*)d_in[33];
  float* out = (float*)d_out;

  // workspace layout (floats)
  float* GA     = (float*)d_ws;                  // 6*256*1152     = 1,769,472
  float* xWrepA = GA     + 1769472;              // 704*1152       =   811,008
  float* xWrepB = xWrepA + 811008;               // 704*48         =    33,792
  float* fbuf   = xWrepB + 33792;                // 704*128        =    90,112
  float* xWB    = fbuf   + 90112;                // 56320*48       = 2,703,360
  float* g2buf  = xWB    + 2703360;              // 56320*16       =   901,120
  float* T2     = g2buf  + 901120;               // 2*256*256      =   131,072
  _Float16* Wpk = (_Float16*)(T2 + 131072);      // 442,368 halves
  _Float16* g1  = (_Float16*)d_out;              // scratch inside output buffer (43.3MB < 115MB)

  hipLaunchKernelGGL(k_frame, dim3(64), dim3(128), 0, stream,
                     feat, periods, embp, c1w, c1b, c2w, c2b, f1w, f1b, f2w, f2b, fbuf);
  hipLaunchKernelGGL(k_wpack4, dim3(1728), dim3(256), 0, stream, ga_whh, Wpk);
  hipLaunchKernelGGL(k_tables, dim3(108), dim3(256), 0, stream, ga_wih, embs, GA);
  hipLaunchKernelGGL(k_t2, dim3(8), dim3(256), 0, stream, m2w1, m2w2, embs, T2);
  hipLaunchKernelGGL(k_xwrepA, dim3(18), dim3(256), 0, stream, ga_wih, fbuf, ga_bih, ga_bhh, xWrepA);
  hipLaunchKernelGGL(k_xwrepB, dim3(64), dim3(256), 0, stream, gb_wih, fbuf, gb_bih, gb_bhh, xWrepB);
  hipLaunchKernelGGL(k_scanA6, dim3(64), dim3(768), 0, stream,
                     in_data, GA, xWrepA, (const uint4*)Wpk, ga_bhh, (unsigned*)g1);
  hipLaunchKernelGGL(k_xwB, dim3(64*55), dim3(256), 0, stream, g1, gb_wih, xWrepB, xWB);
  hipLaunchKernelGGL(k_scanB, dim3(64), dim3(64), 0, stream, xWB, gb_whh, gb_bhh, g2buf);
  hipLaunchKernelGGL(k_out, dim3(64*55), dim3(256), 0, stream,
                     g2buf, targets, T2, m1w1, m1w2, m1b1, m1b2, m1f1, m1f2,
                     m2w1, m2w2, m2b1, m2b2, m2f1, m2f2, out);
}

// Round 8
// 5255.951 us; speedup vs baseline: 2.8487x; 2.8487x over previous
//
#include <hip/hip_runtime.h>
#include <hip/hip_bf16.h>
#include <hip/hip_fp16.h>

#define NF    15
#define NBF   20
#define TT    1760
#define TS    880
#define EP    64
#define ES    128
#define DF    128
#define H1    384
#define G3    1152
#define INA   896
#define JREP  11

typedef _Float16 h2v __attribute__((ext_vector_type(2)));

__device__ __forceinline__ float sigmf_(float x){ return 1.0f/(1.0f + __expf(-x)); }
__device__ __forceinline__ float tanhf_(float x){ return 2.0f/(1.0f + __expf(-2.0f*x)) - 1.0f; }
__device__ __forceinline__ h2v bc_h2(unsigned u){ return __builtin_bit_cast(h2v, u); }
__device__ __forceinline__ float fdot2_(h2v a, h2v b, float c){
#if __has_builtin(__builtin_amdgcn_fdot2)
  return __builtin_amdgcn_fdot2(a, b, c, false);
#else
  return c + (float)a[0]*(float)b[0] + (float)a[1]*(float)b[1];
#endif
}
__device__ __forceinline__ unsigned pk2_(float a, float b){
#if __has_builtin(__builtin_amdgcn_cvt_pkrtz)
  return __builtin_bit_cast(unsigned, __builtin_amdgcn_cvt_pkrtz(a, b));
#else
  unsigned lo = (unsigned)__builtin_bit_cast(unsigned short, (_Float16)a);
  unsigned hi = (unsigned)__builtin_bit_cast(unsigned short, (_Float16)b);
  return lo | (hi << 16);
#endif
}

// ---------------- frame-rate network: f[64][11][128] ----------------
__global__ __launch_bounds__(128) void k_frame(const float* feat, const int* periods, const float* embp,
   const float* c1w, const float* c1b, const float* c2w, const float* c2b,
   const float* f1w, const float* f1b, const float* f2w, const float* f2b, float* fout)
{
  __shared__ float cat[NF*84];
  __shared__ float x1[13*DF];
  __shared__ float x2[JREP*DF];
  int b = blockIdx.x, tid = threadIdx.x;
  for (int idx = tid; idx < NF*84; idx += 128){
    int j = idx/84, c = idx%84;
    cat[idx] = (c < NBF) ? feat[(b*NF+j)*NBF + c]
                         : embp[periods[b*NF+j]*EP + (c-NBF)];
  }
  __syncthreads();
  int o = tid;
  for (int p = 0; p < 13; ++p){
    float acc = c1b[o];
    for (int kk = 0; kk < 3; ++kk)
      for (int c = 0; c < 84; ++c)
        acc += cat[(p+kk)*84 + c] * c1w[(o*84+c)*3+kk];
    x1[p*DF+o] = tanhf_(acc);
  }
  __syncthreads();
  for (int p = 0; p < JREP; ++p){
    float acc = c2b[o];
    for (int kk = 0; kk < 3; ++kk)
      for (int c = 0; c < DF; ++c)
        acc += x1[(p+kk)*DF+c] * c2w[(o*DF+c)*3+kk];
    x2[p*DF+o] = tanhf_(acc);
  }
  __syncthreads();
  for (int p = 0; p < JREP; ++p){
    float acc = f1b[o];
    for (int c = 0; c < DF; ++c) acc += x2[p*DF+c]*f1w[o*DF+c];
    x1[p*DF+o] = tanhf_(acc);
  }
  __syncthreads();
  for (int p = 0; p < JREP; ++p){
    float acc = f2b[o];
    for (int c = 0; c < DF; ++c) acc += x1[p*DF+c]*f2w[o*DF+c];
    fout[(b*JREP+p)*DF+o] = tanhf_(acc);
  }
}

// ---------------- pack ga_whh f32 -> per-(hf,thread) uint4-contiguous f16 ----------------
__global__ __launch_bounds__(256) void k_wpack3(const float* whh, _Float16* wpk){
  int o = blockIdx.x*256 + threadIdx.x;        // < 442368
  int u  = o & 1;
  int c  = (o >> 1) & 3;
  int idx = o >> 3;                            // uint4 index
  int tid = idx % 768;
  int i18 = (idx / 768) % 18;
  int hf  = idx / (768*18);
  int r = tid % 96, s = tid / 96;
  int gd = i18*4 + c;
  int q = gd / 6, k6 = gd % 6;
  int g = k6 >> 1, hsel = k6 & 1;
  int jbase = ((hf ^ (s >> 1))*2 + (s & 1))*48;
  int j = jbase + 4*q + 2*hsel + u;
  int i = hf*96 + r;
  wpk[o] = (_Float16)whh[(g*H1 + i)*H1 + j];
}

// ---------------- GA tables: GA[k][256][1152] ----------------
__global__ __launch_bounds__(256) void k_tables(const float* wih, const float* emb, float* GA){
  __shared__ float Wl[64*129];
  int k = blockIdx.x/18, g0 = (blockIdx.x%18)*64;
  int tid = threadIdx.x;
  for (int idx = tid; idx < 64*128; idx += 256){
    int gg = idx>>7, c = idx&127;
    Wl[gg*129+c] = wih[(size_t)(g0+gg)*INA + k*128 + c];
  }
  __syncthreads();
  int vv = tid>>6, gg = tid&63;
  for (int v = vv; v < 256; v += 4){
    const float* e = emb + (size_t)v*ES;
    float acc = 0.f;
    for (int c = 0; c < 128; ++c) acc += e[c]*Wl[gg*129+c];
    GA[(size_t)(k*256+v)*G3 + g0+gg] = acc;
  }
}

// ---------------- xWrepA[b][j][1152] ----------------
__global__ __launch_bounds__(256) void k_xwrepA(const float* wih, const float* f,
                                                const float* bih, const float* bhh, float* xwA){
  __shared__ float Wl[64*129];
  int g0 = blockIdx.x*64, tid = threadIdx.x;
  for (int idx = tid; idx < 64*128; idx += 256){
    int gg = idx>>7, c = idx&127;
    Wl[gg*129+c] = wih[(size_t)(g0+gg)*INA + 768 + c];
  }
  __syncthreads();
  int vv = tid>>6, gg = tid&63; int g = g0+gg;
  float badd = bih[g] + (g < 768 ? bhh[g] : 0.f);
  for (int row = vv; row < 64*JREP; row += 4){
    const float* fr = f + (size_t)row*DF;
    float acc = badd;
    for (int c = 0; c < 128; ++c) acc += fr[c]*Wl[gg*129+c];
    xwA[(size_t)row*G3 + g] = acc;
  }
}

// ---------------- xWrepB[b][j][48] ----------------
__global__ __launch_bounds__(256) void k_xwrepB(const float* wih, const float* f,
                                                const float* bih, const float* bhh, float* xwB){
  __shared__ float Wl[48*129];
  int b = blockIdx.x, tid = threadIdx.x;
  for (int idx = tid; idx < 48*128; idx += 256){
    int r = idx>>7, c = idx&127;
    Wl[r*129+c] = wih[r*512 + 384 + c];
  }
  __syncthreads();
  for (int idx = tid; idx < JREP*48; idx += 256){
    int j = idx/48, r = idx%48;
    const float* fr = f + (size_t)(b*JREP+j)*DF;
    float acc = bih[r] + (r < 32 ? bhh[r] : 0.f);
    for (int c = 0; c < 128; ++c) acc += fr[c]*Wl[r*129+c];
    xwB[(size_t)(b*JREP+j)*48 + r] = acc;
  }
}

// ---------------- md2 embed tables: T2[tbl][256][256] ----------------
__global__ __launch_bounds__(256) void k_t2(const float* w1, const float* w2, const float* emb, float* T2){
  __shared__ float Wl[64*129];
  int tbl = blockIdx.x>>2; int c0 = (blockIdx.x&3)*64; int tid = threadIdx.x;
  const float* w = tbl ? w2 : w1;
  for (int idx = tid; idx < 64*128; idx += 256){
    int cc = idx>>7, e = idx&127;
    Wl[cc*129+e] = w[(c0+cc)*144 + 16 + e];
  }
  __syncthreads();
  int vv = tid>>6, cc = tid&63;
  for (int v = vv; v < 256; v += 4){
    const float* e = emb + (size_t)v*ES;
    float acc = 0.f;
    for (int c = 0; c < 128; ++c) acc += e[c]*Wl[cc*129+c];
    T2[tbl*65536 + v*256 + c0+cc] = acc;
  }
}

// ---------------- GRU-A scan v8: 4 blocks/batch, seq-tagged f32 exchange (flag-free) ----------------
#define LD18(n) uint4 d##n = wsrc[(size_t)(n)*768];
#define Q2(A,B,C, q2) { \
  h2v hA = bc_h2(hv##q2), hB = bc_h2(hw##q2); \
  ar = fdot2_(hA, bc_h2(A.x), ar); ar = fdot2_(hB, bc_h2(A.y), ar); \
  az = fdot2_(hA, bc_h2(A.z), az); az = fdot2_(hB, bc_h2(A.w), az); \
  an = fdot2_(hA, bc_h2(B.x), an); an = fdot2_(hB, bc_h2(B.y), an); \
  h2v hC = bc_h2(hx##q2), hD = bc_h2(hy##q2); \
  ar = fdot2_(hC, bc_h2(B.z), ar); ar = fdot2_(hD, bc_h2(B.w), ar); \
  az = fdot2_(hC, bc_h2(C.x), az); az = fdot2_(hD, bc_h2(C.y), az); \
  an = fdot2_(hC, bc_h2(C.z), an); an = fdot2_(hD, bc_h2(C.w), an); }
#define DOTS12 \
  Q2(d0,d1,d2,0) Q2(d3,d4,d5,1) Q2(d6,d7,d8,2) \
  Q2(d9,d10,d11,3) Q2(d12,d13,d14,4) Q2(d15,d16,d17,5)

#define PL(n) { unsigned w = __hip_atomic_load(hp+(n), __ATOMIC_RELAXED, __HIP_MEMORY_SCOPE_AGENT); \
                wv##n = w; ok &= ((w & 4095u) == tg); }

__global__ __launch_bounds__(768, 3) void k_scanA8(const int* __restrict__ in_data,
        const float* __restrict__ GA, const float* __restrict__ xwA,
        const uint4* __restrict__ wpk, const float* __restrict__ bhh,
        unsigned* __restrict__ g1u, unsigned* hxf)
{
  __shared__ __align__(16) unsigned h16u[48];        // own-quarter h (u32 = 2 f16 rows)
  __shared__ __align__(8)  float pg[3][8][96];       // partials [gate][grp][row]
  __shared__ __align__(8)  float part[2][2][3][96];  // xW partials [buf][crew][gate][row]
  __shared__ int indr[2][8];
  const int P = blockIdx.x;
  const int b = P & 63, hf = P >> 6;
  const int tid = threadIdx.x;
  const int r = tid % 96, grp = tid / 96;
  const int qq = grp >> 1, par = grp & 1;
  const int qt = hf ^ qq;                      // h-quarter this thread consumes
  const int* ind_b = in_data + (size_t)b*TT*3;

  // weights: 18 uint4, loaded once (R3/R4-proven resident)
  const uint4* wsrc = wpk + (size_t)(hf*18)*768 + tid;
  LD18(0) LD18(1) LD18(2) LD18(3) LD18(4) LD18(5) LD18(6) LD18(7) LD18(8)
  LD18(9) LD18(10) LD18(11) LD18(12) LD18(13) LD18(14) LD18(15) LD18(16) LD18(17)

  const bool isA = (tid >= 192 && tid < 480);
  const bool isB = (tid >= 480);
  const int  cc  = isA ? (tid-192) : (tid-480);
  const int  col = (cc/96)*H1 + hf*96 + (cc%96);

  float hreg0 = 0.f, hreg1 = 0.f, bn0 = 0.f, bn1 = 0.f;
  if (tid < 48){
    bn0 = bhh[768 + hf*96 + 2*tid];
    bn1 = bhh[768 + hf*96 + 2*tid + 1];
    h16u[tid] = 0u;
  }
  // prologue: xW parts for t=0 ; indices for t=1
  if (isA){
    float a0 = GA[((size_t)0*256 + ind_b[0])*G3 + col];
    float a1 = GA[((size_t)1*256 + ind_b[1])*G3 + col];
    float a2 = GA[((size_t)2*256 + ind_b[2])*G3 + col];
    part[0][0][cc/96][cc%96] = a0+a1+a2;
  } else if (isB){
    float a0 = GA[((size_t)3*256 + ind_b[3])*G3 + col];
    float a1 = GA[((size_t)4*256 + ind_b[4])*G3 + col];
    float a2 = GA[((size_t)5*256 + ind_b[5])*G3 + col];
    float a3 = xwA[((size_t)b*JREP + 0)*G3 + col];
    part[0][1][cc/96][cc%96] = a0+a1+a2+a3;
  }
  if (tid >= 192 && tid < 198) indr[1][tid-192] = ind_b[6 + (tid-192)];

  const unsigned* hxq = hxf + ((size_t)(b*4 + qt)*2)*96 + par*48;  // partner rows (f32-tagged)
  unsigned* hxo = hxf + ((size_t)(b*4 + hf)*2)*96;
  __syncthreads();

  for (int t = 0; t < TS; ++t){
    const int nb = t & 1;
    // ---- acquire h source into 24 h2v-u32 regs ----
    unsigned hv0,hw0,hx0,hy0, hv1,hw1,hx1,hy1, hv2,hw2,hx2,hy2;
    unsigned hv3,hw3,hx3,hy3, hv4,hw4,hx4,hy4, hv5,hw5,hx5,hy5;
    if (qq == 0){
      const uint4* hp4 = (const uint4*)&h16u[par*24];
      uint4 a = hp4[0], bq = hp4[1], c2 = hp4[2], dd = hp4[3], e = hp4[4], f = hp4[5];
      hv0=a.x; hw0=a.y; hx0=a.z; hy0=a.w;
      hv1=bq.x;hw1=bq.y;hx1=bq.z;hy1=bq.w;
      hv2=c2.x;hw2=c2.y;hx2=c2.z;hy2=c2.w;
      hv3=dd.x;hw3=dd.y;hx3=dd.z;hy3=dd.w;
      hv4=e.x; hw4=e.y; hx4=e.z; hy4=e.w;
      hv5=f.x; hw5=f.y; hx5=f.z; hy5=f.w;
    } else if (t == 0){
      hv0=hw0=hx0=hy0=hv1=hw1=hx1=hy1=hv2=hw2=hx2=hy2=0u;
      hv3=hw3=hx3=hy3=hv4=hw4=hx4=hy4=hv5=hw5=hx5=hy5=0u;
    } else {
      // tag-poll: load 48 f32 words, each low-12-bit-tagged with (t-1)
      const unsigned* hp = hxq + (size_t)((t+1)&1)*96;
      const unsigned tg = (unsigned)(t-1) & 4095u;
      unsigned wv0,wv1,wv2,wv3,wv4,wv5,wv6,wv7,wv8,wv9,wv10,wv11;
      unsigned wv12,wv13,wv14,wv15,wv16,wv17,wv18,wv19,wv20,wv21,wv22,wv23;
      unsigned wv24,wv25,wv26,wv27,wv28,wv29,wv30,wv31,wv32,wv33,wv34,wv35;
      unsigned wv36,wv37,wv38,wv39,wv40,wv41,wv42,wv43,wv44,wv45,wv46,wv47;
      bool ok;
      do {
        ok = true;
        PL(0)  PL(1)  PL(2)  PL(3)  PL(4)  PL(5)  PL(6)  PL(7)
        PL(8)  PL(9)  PL(10) PL(11) PL(12) PL(13) PL(14) PL(15)
        PL(16) PL(17) PL(18) PL(19) PL(20) PL(21) PL(22) PL(23)
        PL(24) PL(25) PL(26) PL(27) PL(28) PL(29) PL(30) PL(31)
        PL(32) PL(33) PL(34) PL(35) PL(36) PL(37) PL(38) PL(39)
        PL(40) PL(41) PL(42) PL(43) PL(44) PL(45) PL(46) PL(47)
        if (!ok) __builtin_amdgcn_s_sleep(1);
      } while (!ok);
      __builtin_amdgcn_sched_barrier(0);
      #define F32(n) __builtin_bit_cast(float, wv##n)
      hv0=pk2_(F32(0),F32(1));   hw0=pk2_(F32(2),F32(3));
      hx0=pk2_(F32(4),F32(5));   hy0=pk2_(F32(6),F32(7));
      hv1=pk2_(F32(8),F32(9));   hw1=pk2_(F32(10),F32(11));
      hx1=pk2_(F32(12),F32(13)); hy1=pk2_(F32(14),F32(15));
      hv2=pk2_(F32(16),F32(17)); hw2=pk2_(F32(18),F32(19));
      hx2=pk2_(F32(20),F32(21)); hy2=pk2_(F32(22),F32(23));
      hv3=pk2_(F32(24),F32(25)); hw3=pk2_(F32(26),F32(27));
      hx3=pk2_(F32(28),F32(29)); hy3=pk2_(F32(30),F32(31));
      hv4=pk2_(F32(32),F32(33)); hw4=pk2_(F32(34),F32(35));
      hx4=pk2_(F32(36),F32(37)); hy4=pk2_(F32(38),F32(39));
      hv5=pk2_(F32(40),F32(41)); hw5=pk2_(F32(42),F32(43));
      hx5=pk2_(F32(44),F32(45)); hy5=pk2_(F32(46),F32(47));
      #undef F32
    }
    // ---- crews: issue gathers for t+1 (values used after dots) ----
    const int tp = t + 1;
    float gv0=0.f, gv1=0.f, gv2=0.f, gv3=0.f;
    if (tp < TS){
      if (isA){
        gv0 = GA[((size_t)0*256 + indr[tp&1][0])*G3 + col];
        gv1 = GA[((size_t)1*256 + indr[tp&1][1])*G3 + col];
        gv2 = GA[((size_t)2*256 + indr[tp&1][2])*G3 + col];
      } else if (isB){
        gv0 = GA[((size_t)3*256 + indr[tp&1][3])*G3 + col];
        gv1 = GA[((size_t)4*256 + indr[tp&1][4])*G3 + col];
        gv2 = GA[((size_t)5*256 + indr[tp&1][5])*G3 + col];
        gv3 = xwA[((size_t)b*JREP + tp/80)*G3 + col];
      }
    }
    int iv = 0;
    const int stg = t + 2;
    const bool doStg = (tid >= 192 && tid < 198 && stg < TS);
    if (doStg) iv = ind_b[6*stg + (tid-192)];
    // ---- dots ----
    float ar=0.f, az=0.f, an=0.f;
    DOTS12
    pg[0][grp][r] = ar; pg[1][grp][r] = az; pg[2][grp][r] = an;
    // ---- crews finalize ----
    if (tp < TS){
      if (isA)      part[tp&1][0][cc/96][cc%96] = gv0+gv1+gv2;
      else if (isB) part[tp&1][1][cc/96][cc%96] = gv0+gv1+gv2+gv3;
    }
    if (doStg) indr[t&1][tid-192] = iv;
    __syncthreads();
    // ---- epilogue: wave 0, 48 lanes, 2 rows each ----
    if (tid < 48){
      float R = 0.f, Z = 0.f, Gn = 0.f, R1 = 0.f, Z1 = 0.f, Gn1 = 0.f;
      #pragma unroll
      for (int gp = 0; gp < 8; ++gp){
        float2 p0 = *(const float2*)&pg[0][gp][2*tid];
        float2 p1 = *(const float2*)&pg[1][gp][2*tid];
        float2 p2 = *(const float2*)&pg[2][gp][2*tid];
        R += p0.x; R1 += p0.y; Z += p1.x; Z1 += p1.y; Gn += p2.x; Gn1 += p2.y;
      }
      float2 xa0 = *(const float2*)&part[nb][0][0][2*tid];
      float2 xa1 = *(const float2*)&part[nb][0][1][2*tid];
      float2 xa2 = *(const float2*)&part[nb][0][2][2*tid];
      float2 xb0 = *(const float2*)&part[nb][1][0][2*tid];
      float2 xb1 = *(const float2*)&part[nb][1][1][2*tid];
      float2 xb2 = *(const float2*)&part[nb][1][2][2*tid];
      float rr0 = sigmf_(R  + xa0.x + xb0.x);
      float zz0 = sigmf_(Z  + xa1.x + xb1.x);
      float nn0 = tanhf_(xa2.x + xb2.x + rr0*(Gn + bn0));
      float h0 = (1.f - zz0)*nn0 + zz0*hreg0; hreg0 = h0;
      float rr1 = sigmf_(R1 + xa0.y + xb0.y);
      float zz1 = sigmf_(Z1 + xa1.y + xb1.y);
      float nn1 = tanhf_(xa2.y + xb2.y + rr1*(Gn1 + bn1));
      float h1 = (1.f - zz1)*nn1 + zz1*hreg1; hreg1 = h1;
      // publish: seq-tagged f32 words (low 12 mantissa bits = t) — no flag, no drain
      unsigned tw0 = (__builtin_bit_cast(unsigned, h0) & 0xFFFFF000u) | (unsigned)(t & 4095);
      unsigned tw1 = (__builtin_bit_cast(unsigned, h1) & 0xFFFFF000u) | (unsigned)(t & 4095);
      unsigned* ho = hxo + (size_t)nb*96;
      __hip_atomic_store(ho + 2*tid,     tw0, __ATOMIC_RELAXED, __HIP_MEMORY_SCOPE_AGENT);
      __hip_atomic_store(ho + 2*tid + 1, tw1, __ATOMIC_RELAXED, __HIP_MEMORY_SCOPE_AGENT);
      unsigned pack = pk2_(h0, h1);
      h16u[tid] = pack;
      g1u[((size_t)b*TS + t)*192 + hf*48 + tid] = pack;
    }
    __syncthreads();
  }
}

// ---------------- xW_B = g1 @ gb_wih[:, :384].T + xWrepB ----------------
__global__ __launch_bounds__(256) void k_xwB(const _Float16* g1, const float* wih,
                                             const float* xwrB, float* xwB){
  __shared__ _Float16 gl[16*392];
  int bi = blockIdx.x; int b = bi/55; int t0 = (bi%55)*16; int tid = threadIdx.x;
  for (int idx = tid; idx < 16*H1; idx += 256){
    int tt = idx/H1, c = idx%H1;
    gl[tt*392+c] = g1[((size_t)b*TS + t0+tt)*H1 + c];
  }
  __syncthreads();
  int rr = tid>>4, tt = tid&15;
  int t = t0+tt;
  const float* xr = xwrB + ((size_t)(b*JREP) + t/80)*48;
  for (int rb = 0; rb < 3; ++rb){
    int r = rb*16 + rr;
    const float* wrow = wih + (size_t)r*512;
    float acc = 0.f;
    for (int c = 0; c < H1; ++c) acc += (float)gl[tt*392+c]*wrow[c];
    xwB[((size_t)b*TS + t)*48 + r] = acc + xr[r];
  }
}

// ---------------- GRU-B scan (tiny) ----------------
__global__ __launch_bounds__(64) void k_scanB(const float* xwB, const float* whh,
                                              const float* bhh, float* g2){
  __shared__ float wl[48*17];
  __shared__ float h2s[16];
  __shared__ float pre[32];
  __shared__ float xn[16], gn[16];
  int b = blockIdx.x, tid = threadIdx.x;
  for (int idx = tid; idx < 768; idx += 64) wl[(idx>>4)*17 + (idx&15)] = whh[idx];
  if (tid < 16) h2s[tid] = 0.f;
  float bn = (tid >= 32 && tid < 48) ? bhh[tid] : 0.f;
  __syncthreads();
  for (int t = 0; t < TS; ++t){
    if (tid < 48){
      float xw = xwB[((size_t)b*TS + t)*48 + tid];
      float gh = 0.f;
      for (int e = 0; e < 16; ++e) gh += wl[tid*17+e]*h2s[e];
      if (tid < 32) pre[tid] = xw + gh;
      else { xn[tid-32] = xw; gn[tid-32] = gh + bn; }
    }
    __syncthreads();
    if (tid < 16){
      float r = sigmf_(pre[tid]), z = sigmf_(pre[16+tid]);
      float n = tanhf_(xn[tid] + r*gn[tid]);
      float hn = (1.f - z)*n + z*h2s[tid];
      h2s[tid] = hn;
      g2[((size_t)b*TS + t)*16 + tid] = hn;
    }
    __syncthreads();
  }
}

// ---------------- mdense + output interleave ----------------
__global__ __launch_bounds__(256) void k_out(const float* g2, const int* targets, const float* T2,
    const float* m1w1, const float* m1w2, const float* m1b1, const float* m1b2,
    const float* m1f1, const float* m1f2,
    const float* m2w1, const float* m2w2, const float* m2b1, const float* m2b2,
    const float* m2f1, const float* m2f2, float* out)
{
  __shared__ float wA[256*17], wB[256*17], wC[256*17], wD[256*17];
  __shared__ float g2l[16*16];
  int bi = blockIdx.x; int b = bi/55; int t0 = (bi%55)*16; int c = threadIdx.x;
  for (int d = 0; d < 16; ++d){
    wA[c*17+d] = m1w1[c*16+d];  wB[c*17+d] = m1w2[c*16+d];
    wC[c*17+d] = m2w1[c*144+d]; wD[c*17+d] = m2w2[c*144+d];
  }
  { int tt = c>>4, d = c&15; g2l[c] = g2[((size_t)b*TS + t0+tt)*16 + d]; }
  __syncthreads();
  float b1a = m1b1[c], b2a = m1b2[c], f1a = m1f1[c], f2a = m1f2[c];
  float b1b = m2b1[c], b2b = m2b2[c], f1b = m2f1[c], f2b = m2f2[c];
  for (int tt = 0; tt < 16; ++tt){
    int t = t0+tt;
    float d1 = b1a, d2 = b2a, e1 = b1b, e2 = b2b;
    for (int d = 0; d < 16; ++d){
      float g = g2l[tt*16+d];
      d1 += g*wA[c*17+d]; d2 += g*wB[c*17+d];
      e1 += g*wC[c*17+d]; e2 += g*wD[c*17+d];
    }
    int v = targets[b*TT + 2*t];
    e1 += T2[v*256+c]; e2 += T2[65536 + v*256+c];
    float o1 = f1a*tanhf_(d1) + f2a*tanhf_(d2);
    float o2 = f1b*tanhf_(e1) + f2b*tanhf_(e2);
    size_t base = ((size_t)b*TS + t)*2*256;
    out[base + c]       = o1;
    out[base + 256 + c] = o2;
  }
}

extern "C" void kernel_launch(void* const* d_in, const int* in_sizes, int n_in,
                              void* d_out, int out_size, void* d_ws, size_t ws_size,
                              hipStream_t stream) {
  const int*   in_data = (const int*)  d_in[0];
  const float* feat    = (const float*)d_in[1];
  const int*   periods = (const int*)  d_in[2];
  const int*   targets = (const int*)  d_in[3];
  const float* embp    = (const float*)d_in[4];
  const float* embs    = (const float*)d_in[5];
  const float* c1w = (const float*)d_in[6];  const float* c1b = (const float*)d_in[7];
  const float* c2w = (const float*)d_in[8];  const float* c2b = (const float*)d_in[9];
  const float* f1w = (const float*)d_in[10]; const float* f1b = (const float*)d_in[11];
  const float* f2w = (const float*)d_in[12]; const float* f2b = (const float*)d_in[13];
  const float* ga_wih = (const float*)d_in[14]; const float* ga_whh = (const float*)d_in[15];
  const float* ga_bih = (const float*)d_in[16]; const float* ga_bhh = (const float*)d_in[17];
  const float* gb_wih = (const float*)d_in[18]; const float* gb_whh = (const float*)d_in[19];
  const float* gb_bih = (const float*)d_in[20]; const float* gb_bhh = (const float*)d_in[21];
  const float* m1w1 = (const float*)d_in[22]; const float* m1w2 = (const float*)d_in[23];
  const float* m1b1 = (const float*)d_in[24]; const float* m1b2 = (const float*)d_in[25];
  const float* m1f1 = (const float*)d_in[26]; const float* m1f2 = (const float*)d_in[27];
  const float* m2w1 = (const float*)d_in[28]; const float* m2w2 = (const float*)d_in[29];
  const float* m2b1 = (const float*)d_in[30]; const float* m2b2 = (const float*)d_in[31];
  const float* m2f1 = (const float*)d_in[32]; const float* m2f2 = (const float*)d_in[33];
  float* out = (float*)d_out;

  // workspace layout (floats)
  float* GA     = (float*)d_ws;                  // 6*256*1152     = 1,769,472
  float* xWrepA = GA     + 1769472;              // 704*1152       =   811,008
  float* xWrepB = xWrepA + 811008;               // 704*48         =    33,792
  float* fbuf   = xWrepB + 33792;                // 704*128        =    90,112
  float* xWB    = fbuf   + 90112;                // 56320*48       = 2,703,360
  float* g2buf  = xWB    + 2703360;              // 56320*16       =   901,120
  float* T2     = g2buf  + 901120;               // 2*256*256      =   131,072
  _Float16* Wpk = (_Float16*)(T2 + 131072);      // 442,368 halves
  unsigned* hxf = (unsigned*)(Wpk + 442368);     // 64*4*2*96 u32  =    49,152
  _Float16* g1  = (_Float16*)d_out;              // scratch inside output buffer (43.3MB < 115MB)

  // invalidate exchange tags each launch (stale cross-replay tags never match)
  (void)hipMemsetAsync(hxf, 0xFF, 49152*sizeof(unsigned), stream);
  hipLaunchKernelGGL(k_frame, dim3(64), dim3(128), 0, stream,
                     feat, periods, embp, c1w, c1b, c2w, c2b, f1w, f1b, f2w, f2b, fbuf);
  hipLaunchKernelGGL(k_wpack3, dim3(1728), dim3(256), 0, stream, ga_whh, Wpk);
  hipLaunchKernelGGL(k_tables, dim3(108), dim3(256), 0, stream, ga_wih, embs, GA);
  hipLaunchKernelGGL(k_t2, dim3(8), dim3(256), 0, stream, m2w1, m2w2, embs, T2);
  hipLaunchKernelGGL(k_xwrepA, dim3(18), dim3(256), 0, stream, ga_wih, fbuf, ga_bih, ga_bhh, xWrepA);
  hipLaunchKernelGGL(k_xwrepB, dim3(64), dim3(256), 0, stream, gb_wih, fbuf, gb_bih, gb_bhh, xWrepB);
  hipLaunchKernelGGL(k_scanA8, dim3(256), dim3(768), 0, stream,
                     in_data, GA, xWrepA, (const uint4*)Wpk, ga_bhh,
                     (unsigned*)g1, hxf);
  hipLaunchKernelGGL(k_xwB, dim3(64*55), dim3(256), 0, stream, g1, gb_wih, xWrepB, xWB);
  hipLaunchKernelGGL(k_scanB, dim3(64), dim3(64), 0, stream, xWB, gb_whh, gb_bhh, g2buf);
  hipLaunchKernelGGL(k_out, dim3(64*55), dim3(256), 0, stream,
                     g2buf, targets, T2, m1w1, m1w2, m1b1, m1b2, m1f1, m1f2,
                     m2w1, m2w2, m2b1, m2b2, m2f1, m2f2, out);
}

// Round 9
// 4093.694 us; speedup vs baseline: 3.6575x; 1.2839x over previous
//
#include <hip/hip_runtime.h>
#include <hip/hip_bf16.h>
#include <hip/hip_fp16.h>

#define NF    15
#define NBF   20
#define TT    1760
#define TS    880
#define EP    64
#define ES    128
#define DF    128
#define H1    384
#define G3    1152
#define INA   896
#define JREP  11

typedef _Float16 h2v __attribute__((ext_vector_type(2)));

__device__ __forceinline__ float sigmf_(float x){ return 1.0f/(1.0f + __expf(-x)); }
__device__ __forceinline__ float tanhf_(float x){ return 2.0f/(1.0f + __expf(-2.0f*x)) - 1.0f; }
__device__ __forceinline__ h2v bc_h2(unsigned u){ return __builtin_bit_cast(h2v, u); }
__device__ __forceinline__ float fdot2_(h2v a, h2v b, float c){
#if __has_builtin(__builtin_amdgcn_fdot2)
  return __builtin_amdgcn_fdot2(a, b, c, false);
#else
  return c + (float)a[0]*(float)b[0] + (float)a[1]*(float)b[1];
#endif
}
__device__ __forceinline__ unsigned pk2_(float a, float b){
#if __has_builtin(__builtin_amdgcn_cvt_pkrtz)
  return __builtin_bit_cast(unsigned, __builtin_amdgcn_cvt_pkrtz(a, b));
#else
  unsigned lo = (unsigned)__builtin_bit_cast(unsigned short, (_Float16)a);
  unsigned hi = (unsigned)__builtin_bit_cast(unsigned short, (_Float16)b);
  return lo | (hi << 16);
#endif
}
__device__ __forceinline__ void bar_lgkm(){
  asm volatile("s_waitcnt lgkmcnt(0)" ::: "memory");
  __builtin_amdgcn_s_barrier();
  __builtin_amdgcn_sched_barrier(0);
}

// ---------------- frame-rate network: f[64][11][128] ----------------
__global__ __launch_bounds__(128) void k_frame(const float* feat, const int* periods, const float* embp,
   const float* c1w, const float* c1b, const float* c2w, const float* c2b,
   const float* f1w, const float* f1b, const float* f2w, const float* f2b, float* fout)
{
  __shared__ float cat[NF*84];
  __shared__ float x1[13*DF];
  __shared__ float x2[JREP*DF];
  int b = blockIdx.x, tid = threadIdx.x;
  for (int idx = tid; idx < NF*84; idx += 128){
    int j = idx/84, c = idx%84;
    cat[idx] = (c < NBF) ? feat[(b*NF+j)*NBF + c]
                         : embp[periods[b*NF+j]*EP + (c-NBF)];
  }
  __syncthreads();
  int o = tid;
  for (int p = 0; p < 13; ++p){
    float acc = c1b[o];
    for (int kk = 0; kk < 3; ++kk)
      for (int c = 0; c < 84; ++c)
        acc += cat[(p+kk)*84 + c] * c1w[(o*84+c)*3+kk];
    x1[p*DF+o] = tanhf_(acc);
  }
  __syncthreads();
  for (int p = 0; p < JREP; ++p){
    float acc = c2b[o];
    for (int kk = 0; kk < 3; ++kk)
      for (int c = 0; c < DF; ++c)
        acc += x1[(p+kk)*DF+c] * c2w[(o*DF+c)*3+kk];
    x2[p*DF+o] = tanhf_(acc);
  }
  __syncthreads();
  for (int p = 0; p < JREP; ++p){
    float acc = f1b[o];
    for (int c = 0; c < DF; ++c) acc += x2[p*DF+c]*f1w[o*DF+c];
    x1[p*DF+o] = tanhf_(acc);
  }
  __syncthreads();
  for (int p = 0; p < JREP; ++p){
    float acc = f2b[o];
    for (int c = 0; c < DF; ++c) acc += x1[p*DF+c]*f2w[o*DF+c];
    fout[(b*JREP+p)*DF+o] = tanhf_(acc);
  }
}

// ---------------- pack ga_whh f32 -> per-(hf,thread) uint4-contiguous f16 (j-quarter split) -------
// consumed by k_scanA9: block hf, thread tid (i=tid%384 output row, u=tid/384 j-half):
//   d_n = wpk4[(hf*18 + n)*768 + tid], n in [0,18)
//   dword gd = n*4+c: m=gd/12, dc=gd%12 ; pos=(dc%2)+2*(dc/6), gate=(dc%6)>>1
//   half hu: j = hf*96 + u*48 + (4m+pos)*2 + hu ; w = whh[(gate*H1+i)*H1 + j]
__global__ __launch_bounds__(256) void k_wpack5(const float* whh, _Float16* wpk){
  int o = blockIdx.x*256 + threadIdx.x;        // < 442368
  int hu = o & 1;
  int c  = (o >> 1) & 3;
  int idx = o >> 3;                            // uint4 index
  int tid = idx % 768;
  int n   = (idx / 768) % 18;
  int hf  = idx / (768*18);
  int i = tid % 384, u = tid / 384;
  int gd = n*4 + c;
  int m = gd / 12, dc = gd % 12;
  int pos  = (dc % 2) + 2*(dc / 6);
  int gate = (dc % 6) >> 1;
  int j = hf*96 + u*48 + (4*m + pos)*2 + hu;
  wpk[o] = (_Float16)whh[(gate*H1 + i)*H1 + j];
}

// ---------------- GA tables: GA[k][256][1152] ----------------
__global__ __launch_bounds__(256) void k_tables(const float* wih, const float* emb, float* GA){
  __shared__ float Wl[64*129];
  int k = blockIdx.x/18, g0 = (blockIdx.x%18)*64;
  int tid = threadIdx.x;
  for (int idx = tid; idx < 64*128; idx += 256){
    int gg = idx>>7, c = idx&127;
    Wl[gg*129+c] = wih[(size_t)(g0+gg)*INA + k*128 + c];
  }
  __syncthreads();
  int vv = tid>>6, gg = tid&63;
  for (int v = vv; v < 256; v += 4){
    const float* e = emb + (size_t)v*ES;
    float acc = 0.f;
    for (int c = 0; c < 128; ++c) acc += e[c]*Wl[gg*129+c];
    GA[(size_t)(k*256+v)*G3 + g0+gg] = acc;
  }
}

// ---------------- xWrepA[b][j][1152] ----------------
__global__ __launch_bounds__(256) void k_xwrepA(const float* wih, const float* f,
                                                const float* bih, const float* bhh, float* xwA){
  __shared__ float Wl[64*129];
  int g0 = blockIdx.x*64, tid = threadIdx.x;
  for (int idx = tid; idx < 64*128; idx += 256){
    int gg = idx>>7, c = idx&127;
    Wl[gg*129+c] = wih[(size_t)(g0+gg)*INA + 768 + c];
  }
  __syncthreads();
  int vv = tid>>6, gg = tid&63; int g = g0+gg;
  float badd = bih[g] + (g < 768 ? bhh[g] : 0.f);
  for (int row = vv; row < 64*JREP; row += 4){
    const float* fr = f + (size_t)row*DF;
    float acc = badd;
    for (int c = 0; c < 128; ++c) acc += fr[c]*Wl[gg*129+c];
    xwA[(size_t)row*G3 + g] = acc;
  }
}

// ---------------- xWrepB[b][j][48] ----------------
__global__ __launch_bounds__(256) void k_xwrepB(const float* wih, const float* f,
                                                const float* bih, const float* bhh, float* xwB){
  __shared__ float Wl[48*129];
  int b = blockIdx.x, tid = threadIdx.x;
  for (int idx = tid; idx < 48*128; idx += 256){
    int r = idx>>7, c = idx&127;
    Wl[r*129+c] = wih[r*512 + 384 + c];
  }
  __syncthreads();
  for (int idx = tid; idx < JREP*48; idx += 256){
    int j = idx/48, r = idx%48;
    const float* fr = f + (size_t)(b*JREP+j)*DF;
    float acc = bih[r] + (r < 32 ? bhh[r] : 0.f);
    for (int c = 0; c < 128; ++c) acc += fr[c]*Wl[r*129+c];
    xwB[(size_t)(b*JREP+j)*48 + r] = acc;
  }
}

// ---------------- md2 embed tables: T2[tbl][256][256] ----------------
__global__ __launch_bounds__(256) void k_t2(const float* w1, const float* w2, const float* emb, float* T2){
  __shared__ float Wl[64*129];
  int tbl = blockIdx.x>>2; int c0 = (blockIdx.x&3)*64; int tid = threadIdx.x;
  const float* w = tbl ? w2 : w1;
  for (int idx = tid; idx < 64*128; idx += 256){
    int cc = idx>>7, e = idx&127;
    Wl[cc*129+e] = w[(c0+cc)*144 + 16 + e];
  }
  __syncthreads();
  int vv = tid>>6, cc = tid&63;
  for (int v = vv; v < 256; v += 4){
    const float* e = emb + (size_t)v*ES;
    float acc = 0.f;
    for (int c = 0; c < 128; ++c) acc += e[c]*Wl[cc*129+c];
    T2[tbl*65536 + v*256 + c0+cc] = acc;
  }
}

// ---------------- GRU-A scan v9: partial-forwarding (dots never wait on remote h) ----------------
#define LD18(n) uint4 d##n = wsrc[(size_t)(n)*768];
#define Q2(A,B,C, q2) { \
  h2v hA = hh[jb2 + (q2)*2],     hB = hh[jb2 + (q2)*2 + 1]; \
  ar = fdot2_(hA, bc_h2(A.x), ar); ar = fdot2_(hB, bc_h2(A.y), ar); \
  az = fdot2_(hA, bc_h2(A.z), az); az = fdot2_(hB, bc_h2(A.w), az); \
  an = fdot2_(hA, bc_h2(B.x), an); an = fdot2_(hB, bc_h2(B.y), an); \
  h2v hC = hh[jb2 + (q2)*2 + 2], hD = hh[jb2 + (q2)*2 + 3]; \
  ar = fdot2_(hC, bc_h2(B.z), ar); ar = fdot2_(hD, bc_h2(B.w), ar); \
  az = fdot2_(hC, bc_h2(C.x), az); az = fdot2_(hD, bc_h2(C.y), az); \
  an = fdot2_(hC, bc_h2(C.z), an); an = fdot2_(hD, bc_h2(C.w), an); }
#define DOTS12 \
  Q2(d0,d1,d2,0) Q2(d3,d4,d5,2) Q2(d6,d7,d8,4) \
  Q2(d9,d10,d11,6) Q2(d12,d13,d14,8) Q2(d15,d16,d17,10)

#define PLW(n, p) { unsigned w = __hip_atomic_load((p), __ATOMIC_RELAXED, __HIP_MEMORY_SCOPE_AGENT); \
                    rv##n = w; ok &= ((w & 1023u) == tg); }

__global__ __launch_bounds__(768, 3) void k_scanA9(const int* __restrict__ in_data,
        const float* __restrict__ GA, const float* __restrict__ xwA,
        const uint4* __restrict__ wpk, const float* __restrict__ bhh,
        unsigned* __restrict__ g1u, unsigned* pbuf)
{
  __shared__ __align__(16) unsigned h16u[48];     // own j-quarter h(t-1): 96 rows = 48 u32
  __shared__ __align__(8)  float pg[3][2][384];   // own-quarter partials [gate][u][out-row]
  __shared__ __align__(8)  float xwb[2][G3];      // xW double buffer
  __shared__ int indr[2][8];
  const int P = blockIdx.x;
  const int b = P & 63, hf = P >> 6;
  const int tid = threadIdx.x;
  const int i  = tid % 384;                       // output row (global)
  const int u  = tid / 384;                       // j-half of own quarter
  const int jb2 = u * 24;                         // h2 base into h16u
  const int* ind_b = in_data + (size_t)b*TT*3;

  // weights: 18 uint4 (j-quarter slice), loaded once — R3/R4-proven resident
  const uint4* wsrc = wpk + (size_t)(hf*18)*768 + tid;
  LD18(0) LD18(1) LD18(2) LD18(3) LD18(4) LD18(5) LD18(6) LD18(7) LD18(8)
  LD18(9) LD18(10) LD18(11) LD18(12) LD18(13) LD18(14) LD18(15) LD18(16) LD18(17)

  const bool isGat = (tid < 576);
  const int  c0 = 2*tid, c1 = 2*tid + 1;          // gather col pair (isGat)
  const bool isPub = (tid >= 96 && tid < 672);
  const int  po0 = 2*(tid - 96);                  // publish output pair (isPub)

  float hreg0 = 0.f, hreg1 = 0.f, bn0 = 0.f, bn1 = 0.f;
  if (tid < 48){
    bn0 = bhh[768 + hf*96 + 2*tid];
    bn1 = bhh[768 + hf*96 + 2*tid + 1];
    h16u[tid] = 0u;
  }
  // prologue: xwb[0] for t=0 ; indices for t=1
  if (isGat){
    float s0 = xwA[(size_t)(b*JREP)*G3 + c0];
    float s1 = xwA[(size_t)(b*JREP)*G3 + c1];
    #pragma unroll
    for (int k2 = 0; k2 < 6; ++k2){
      int v = ind_b[k2];
      s0 += GA[((size_t)k2*256 + v)*G3 + c0];
      s1 += GA[((size_t)k2*256 + v)*G3 + c1];
    }
    xwb[0][c0] = s0; xwb[0][c1] = s1;
  }
  if (tid >= 576 && tid < 582) indr[1][tid-576] = ind_b[6 + (tid-576)];

  unsigned* pbo = pbuf + ((size_t)(b*4 + hf)*2)*G3;                 // own publish base
  const int pf1 = (hf+1)&3, pf2 = (hf+2)&3, pf3 = (hf+3)&3;
  const unsigned* pb1 = pbuf + ((size_t)(b*4 + pf1)*2)*G3 + hf*96 + 2*(tid<48?tid:0);
  const unsigned* pb2 = pbuf + ((size_t)(b*4 + pf2)*2)*G3 + hf*96 + 2*(tid<48?tid:0);
  const unsigned* pb3 = pbuf + ((size_t)(b*4 + pf3)*2)*G3 + hf*96 + 2*(tid<48?tid:0);
  const h2v* hh = (const h2v*)h16u;
  __syncthreads();

  for (int t = 0; t < TS; ++t){
    const int nb = t & 1;
    // ---- phase 1: issue xW gathers for t+1, dots on OWN h-quarter (no remote wait) ----
    const int tp = t + 1;
    float ga0=0.f,ga1=0.f,ga2=0.f,ga3=0.f,ga4=0.f,ga5=0.f,gx0=0.f;
    float gb0=0.f,gb1=0.f,gb2=0.f,gb3=0.f,gb4=0.f,gb5=0.f,gx1=0.f;
    if (tp < TS && isGat){
      int v0=indr[tp&1][0], v1=indr[tp&1][1], v2=indr[tp&1][2];
      int v3=indr[tp&1][3], v4=indr[tp&1][4], v5=indr[tp&1][5];
      const float* xwr = xwA + ((size_t)(b*JREP) + tp/80)*G3;
      ga0 = GA[((size_t)0*256 + v0)*G3 + c0]; gb0 = GA[((size_t)0*256 + v0)*G3 + c1];
      ga1 = GA[((size_t)1*256 + v1)*G3 + c0]; gb1 = GA[((size_t)1*256 + v1)*G3 + c1];
      ga2 = GA[((size_t)2*256 + v2)*G3 + c0]; gb2 = GA[((size_t)2*256 + v2)*G3 + c1];
      ga3 = GA[((size_t)3*256 + v3)*G3 + c0]; gb3 = GA[((size_t)3*256 + v3)*G3 + c1];
      ga4 = GA[((size_t)4*256 + v4)*G3 + c0]; gb4 = GA[((size_t)4*256 + v4)*G3 + c1];
      ga5 = GA[((size_t)5*256 + v5)*G3 + c0]; gb5 = GA[((size_t)5*256 + v5)*G3 + c1];
      gx0 = xwr[c0]; gx1 = xwr[c1];
    }
    int iv = 0;
    const int stg = t + 2;
    const bool doStg = (tid >= 576 && tid < 582 && stg < TS);
    if (doStg) iv = ind_b[6*stg + (tid-576)];
    // dots: 72 fdot2 against resident weights; h from own-quarter LDS (broadcast reads)
    float ar=0.f, az=0.f, an=0.f;
    DOTS12
    pg[0][u][i] = ar; pg[1][u][i] = az; pg[2][u][i] = an;
    if (tp < TS && isGat){
      xwb[tp&1][c0] = ga0+ga1+ga2+ga3+ga4+ga5+gx0;
      xwb[tp&1][c1] = gb0+gb1+gb2+gb3+gb4+gb5+gx1;
    }
    if (doStg) indr[t&1][tid-576] = iv;
    bar_lgkm();
    // ---- phase 2: publishers push tagged partials; epilogue lanes poll + update h ----
    if (isPub){
      int g = po0/384, ii = po0 - g*384;
      float2 p0 = *(const float2*)&pg[g][0][ii];
      float2 p1 = *(const float2*)&pg[g][1][ii];
      float v0 = p0.x + p1.x, v1 = p0.y + p1.y;
      unsigned tw0 = (__builtin_bit_cast(unsigned, v0) & 0xFFFFFC00u) | (unsigned)t;
      unsigned tw1 = (__builtin_bit_cast(unsigned, v1) & 0xFFFFFC00u) | (unsigned)t;
      unsigned* dst = pbo + (size_t)nb*G3 + po0;
      __hip_atomic_store(dst,     tw0, __ATOMIC_RELAXED, __HIP_MEMORY_SCOPE_AGENT);
      __hip_atomic_store(dst + 1, tw1, __ATOMIC_RELAXED, __HIP_MEMORY_SCOPE_AGENT);
    } else if (tid < 48){
      const unsigned tg = (unsigned)t;
      const unsigned* q1 = pb1 + (size_t)nb*G3;
      const unsigned* q2 = pb2 + (size_t)nb*G3;
      const unsigned* q3 = pb3 + (size_t)nb*G3;
      unsigned rv0,rv1,rv2,rv3,rv4,rv5,rv6,rv7,rv8;
      unsigned rv9,rv10,rv11,rv12,rv13,rv14,rv15,rv16,rv17;
      bool ok;
      do {
        ok = true;
        PLW(0,  q1+0) PLW(1,  q1+1) PLW(2,  q1+384) PLW(3,  q1+385) PLW(4,  q1+768) PLW(5,  q1+769)
        PLW(6,  q2+0) PLW(7,  q2+1) PLW(8,  q2+384) PLW(9,  q2+385) PLW(10, q2+768) PLW(11, q2+769)
        PLW(12, q3+0) PLW(13, q3+1) PLW(14, q3+384) PLW(15, q3+385) PLW(16, q3+768) PLW(17, q3+769)
        if (!ok) __builtin_amdgcn_s_sleep(1);
      } while (!ok);
      __builtin_amdgcn_sched_barrier(0);
      #define FV(n) __builtin_bit_cast(float, rv##n & 0xFFFFFC00u)
      int i0 = hf*96 + 2*tid;
      float2 o0 = *(const float2*)&pg[0][0][i0];  float2 o0b = *(const float2*)&pg[0][1][i0];
      float2 o1 = *(const float2*)&pg[1][0][i0];  float2 o1b = *(const float2*)&pg[1][1][i0];
      float2 o2 = *(const float2*)&pg[2][0][i0];  float2 o2b = *(const float2*)&pg[2][1][i0];
      float2 xr = *(const float2*)&xwb[nb][i0];
      float2 xz = *(const float2*)&xwb[nb][384 + i0];
      float2 xn = *(const float2*)&xwb[nb][768 + i0];
      float R0 = o0.x + o0b.x + FV(0)  + FV(6)  + FV(12) + xr.x;
      float R1 = o0.y + o0b.y + FV(1)  + FV(7)  + FV(13) + xr.y;
      float Z0 = o1.x + o1b.x + FV(2)  + FV(8)  + FV(14) + xz.x;
      float Z1 = o1.y + o1b.y + FV(3)  + FV(9)  + FV(15) + xz.y;
      float G0 = o2.x + o2b.x + FV(4)  + FV(10) + FV(16) + bn0;
      float G1 = o2.y + o2b.y + FV(5)  + FV(11) + FV(17) + bn1;
      #undef FV
      float rr0 = sigmf_(R0), zz0 = sigmf_(Z0);
      float nn0 = tanhf_(xn.x + rr0*G0);
      float h0 = (1.f - zz0)*nn0 + zz0*hreg0; hreg0 = h0;
      float rr1 = sigmf_(R1), zz1 = sigmf_(Z1);
      float nn1 = tanhf_(xn.y + rr1*G1);
      float h1 = (1.f - zz1)*nn1 + zz1*hreg1; hreg1 = h1;
      unsigned pack = pk2_(h0, h1);
      h16u[tid] = pack;
      g1u[((size_t)b*TS + t)*192 + hf*48 + tid] = pack;
    }
    bar_lgkm();
  }
}

// ---------------- xW_B = g1 @ gb_wih[:, :384].T + xWrepB ----------------
__global__ __launch_bounds__(256) void k_xwB(const _Float16* g1, const float* wih,
                                             const float* xwrB, float* xwB){
  __shared__ _Float16 gl[16*392];
  int bi = blockIdx.x; int b = bi/55; int t0 = (bi%55)*16; int tid = threadIdx.x;
  for (int idx = tid; idx < 16*H1; idx += 256){
    int tt = idx/H1, c = idx%H1;
    gl[tt*392+c] = g1[((size_t)b*TS + t0+tt)*H1 + c];
  }
  __syncthreads();
  int rr = tid>>4, tt = tid&15;
  int t = t0+tt;
  const float* xr = xwrB + ((size_t)(b*JREP) + t/80)*48;
  for (int rb = 0; rb < 3; ++rb){
    int r = rb*16 + rr;
    const float* wrow = wih + (size_t)r*512;
    float acc = 0.f;
    for (int c = 0; c < H1; ++c) acc += (float)gl[tt*392+c]*wrow[c];
    xwB[((size_t)b*TS + t)*48 + r] = acc + xr[r];
  }
}

// ---------------- GRU-B scan (tiny) ----------------
__global__ __launch_bounds__(64) void k_scanB(const float* xwB, const float* whh,
                                              const float* bhh, float* g2){
  __shared__ float wl[48*17];
  __shared__ float h2s[16];
  __shared__ float pre[32];
  __shared__ float xn[16], gn[16];
  int b = blockIdx.x, tid = threadIdx.x;
  for (int idx = tid; idx < 768; idx += 64) wl[(idx>>4)*17 + (idx&15)] = whh[idx];
  if (tid < 16) h2s[tid] = 0.f;
  float bn = (tid >= 32 && tid < 48) ? bhh[tid] : 0.f;
  __syncthreads();
  for (int t = 0; t < TS; ++t){
    if (tid < 48){
      float xw = xwB[((size_t)b*TS + t)*48 + tid];
      float gh = 0.f;
      for (int e = 0; e < 16; ++e) gh += wl[tid*17+e]*h2s[e];
      if (tid < 32) pre[tid] = xw + gh;
      else { xn[tid-32] = xw; gn[tid-32] = gh + bn; }
    }
    __syncthreads();
    if (tid < 16){
      float r = sigmf_(pre[tid]), z = sigmf_(pre[16+tid]);
      float n = tanhf_(xn[tid] + r*gn[tid]);
      float hn = (1.f - z)*n + z*h2s[tid];
      h2s[tid] = hn;
      g2[((size_t)b*TS + t)*16 + tid] = hn;
    }
    __syncthreads();
  }
}

// ---------------- mdense + output interleave ----------------
__global__ __launch_bounds__(256) void k_out(const float* g2, const int* targets, const float* T2,
    const float* m1w1, const float* m1w2, const float* m1b1, const float* m1b2,
    const float* m1f1, const float* m1f2,
    const float* m2w1, const float* m2w2, const float* m2b1, const float* m2b2,
    const float* m2f1, const float* m2f2, float* out)
{
  __shared__ float wA[256*17], wB[256*17], wC[256*17], wD[256*17];
  __shared__ float g2l[16*16];
  int bi = blockIdx.x; int b = bi/55; int t0 = (bi%55)*16; int c = threadIdx.x;
  for (int d = 0; d < 16; ++d){
    wA[c*17+d] = m1w1[c*16+d];  wB[c*17+d] = m1w2[c*16+d];
    wC[c*17+d] = m2w1[c*144+d]; wD[c*17+d] = m2w2[c*144+d];
  }
  { int tt = c>>4, d = c&15; g2l[c] = g2[((size_t)b*TS + t0+tt)*16 + d]; }
  __syncthreads();
  float b1a = m1b1[c], b2a = m1b2[c], f1a = m1f1[c], f2a = m1f2[c];
  float b1b = m2b1[c], b2b = m2b2[c], f1b = m2f1[c], f2b = m2f2[c];
  for (int tt = 0; tt < 16; ++tt){
    int t = t0+tt;
    float d1 = b1a, d2 = b2a, e1 = b1b, e2 = b2b;
    for (int d = 0; d < 16; ++d){
      float g = g2l[tt*16+d];
      d1 += g*wA[c*17+d]; d2 += g*wB[c*17+d];
      e1 += g*wC[c*17+d]; e2 += g*wD[c*17+d];
    }
    int v = targets[b*TT + 2*t];
    e1 += T2[v*256+c]; e2 += T2[65536 + v*256+c];
    float o1 = f1a*tanhf_(d1) + f2a*tanhf_(d2);
    float o2 = f1b*tanhf_(e1) + f2b*tanhf_(e2);
    size_t base = ((size_t)b*TS + t)*2*256;
    out[base + c]       = o1;
    out[base + 256 + c] = o2;
  }
}

extern "C" void kernel_launch(void* const* d_in, const int* in_sizes, int n_in,
                              void* d_out, int out_size, void* d_ws, size_t ws_size,
                              hipStream_t stream) {
  const int*   in_data = (const int*)  d_in[0];
  const float* feat    = (const float*)d_in[1];
  const int*   periods = (const int*)  d_in[2];
  const int*   targets = (const int*)  d_in[3];
  const float* embp    = (const float*)d_in[4];
  const float* embs    = (const float*)d_in[5];
  const float* c1w = (const float*)d_in[6];  const float* c1b = (const float*)d_in[7];
  const float* c2w = (const float*)d_in[8];  const float* c2b = (const float*)d_in[9];
  const float* f1w = (const float*)d_in[10]; const float* f1b = (const float*)d_in[11];
  const float* f2w = (const float*)d_in[12]; const float* f2b = (const float*)d_in[13];
  const float* ga_wih = (const float*)d_in[14]; const float* ga_whh = (const float*)d_in[15];
  const float* ga_bih = (const float*)d_in[16]; const float* ga_bhh = (const float*)d_in[17];
  const float* gb_wih = (const float*)d_in[18]; const float* gb_whh = (const float*)d_in[19];
  const float* gb_bih = (const float*)d_in[20]; const float* gb_bhh = (const float*)d_in[21];
  const float* m1w1 = (const float*)d_in[22]; const float* m1w2 = (const float*)d_in[23];
  const float* m1b1 = (const float*)d_in[24]; const float* m1b2 = (const float*)d_in[25];
  const float* m1f1 = (const float*)d_in[26]; const float* m1f2 = (const float*)d_in[27];
  const float* m2w1 = (const float*)d_in[28]; const float* m2w2 = (const float*)d_in[29];
  const float* m2b1 = (const float*)d_in[30]; const float* m2b2 = (const float*)d_in[31];
  const float* m2f1 = (const float*)d_in[32]; const float* m2f2 = (const float*)d_in[33];
  float* out = (float*)d_out;

  // workspace layout (floats)
  float* GA     = (float*)d_ws;                  // 6*256*1152     = 1,769,472
  float* xWrepA = GA     + 1769472;              // 704*1152       =   811,008
  float* xWrepB = xWrepA + 811008;               // 704*48         =    33,792
  float* fbuf   = xWrepB + 33792;                // 704*128        =    90,112
  float* xWB    = fbuf   + 90112;                // 56320*48       = 2,703,360
  float* g2buf  = xWB    + 2703360;              // 56320*16       =   901,120
  float* T2     = g2buf  + 901120;               // 2*256*256      =   131,072
  _Float16* Wpk = (_Float16*)(T2 + 131072);      // 442,368 halves
  unsigned* pbuf = (unsigned*)(Wpk + 442368);    // 64*4*2*1152 u32 = 589,824
  _Float16* g1  = (_Float16*)d_out;              // scratch inside output buffer (43.3MB < 115MB)

  // invalidate partial-tags each launch (stale tag 1023 never matches any t<880)
  (void)hipMemsetAsync(pbuf, 0xFF, 589824*sizeof(unsigned), stream);
  hipLaunchKernelGGL(k_frame, dim3(64), dim3(128), 0, stream,
                     feat, periods, embp, c1w, c1b, c2w, c2b, f1w, f1b, f2w, f2b, fbuf);
  hipLaunchKernelGGL(k_wpack5, dim3(1728), dim3(256), 0, stream, ga_whh, Wpk);
  hipLaunchKernelGGL(k_tables, dim3(108), dim3(256), 0, stream, ga_wih, embs, GA);
  hipLaunchKernelGGL(k_t2, dim3(8), dim3(256), 0, stream, m2w1, m2w2, embs, T2);
  hipLaunchKernelGGL(k_xwrepA, dim3(18), dim3(256), 0, stream, ga_wih, fbuf, ga_bih, ga_bhh, xWrepA);
  hipLaunchKernelGGL(k_xwrepB, dim3(64), dim3(256), 0, stream, gb_wih, fbuf, gb_bih, gb_bhh, xWrepB);
  hipLaunchKernelGGL(k_scanA9, dim3(256), dim3(768), 0, stream,
                     in_data, GA, xWrepA, (const uint4*)Wpk, ga_bhh,
                     (unsigned*)g1, pbuf);
  hipLaunchKernelGGL(k_xwB, dim3(64*55), dim3(256), 0, stream, g1, gb_wih, xWrepB, xWB);
  hipLaunchKernelGGL(k_scanB, dim3(64), dim3(64), 0, stream, xWB, gb_whh, gb_bhh, g2buf);
  hipLaunchKernelGGL(k_out, dim3(64*55), dim3(256), 0, stream,
                     g2buf, targets, T2, m1w1, m1w2, m1b1, m1b2, m1f1, m1f2,
                     m2w1, m2w2, m2b1, m2b2, m2f1, m2f2, out);
}